// Round 15
// baseline (417.422 us; speedup 1.0000x reference)
//
#include <hip/hip_runtime.h>
#include <cmath>

#define CAPB 64    // padded bucket capacity; deg~Poisson(16), P(>64)~1e-21; overflow list for safety
#define CAP0 192   // max staged degree in fused kernels (bucket + appended overflow)
#define SWS  196   // s_w row stride: 196%32=4 -> 8 head-rows hit distinct banks
#define CSTR 16    // cnt stride in ints: one counter per 64B cacheline (kills L2 line-bouncing)
#define G0_ROWS 64
#define G0_PAD 68

// ---------------- merged: edge scatter (all blocks) + GEMM0 tile (first blocks) ----------
__global__ void k_gemm0_scatter(const float* __restrict__ x, const float* __restrict__ W0,
                                const float* __restrict__ al, const float* __restrict__ ar,
                                const int* __restrict__ dst, const int* __restrict__ src,
                                float* __restrict__ f0, float* __restrict__ el,
                                float* __restrict__ er, int* __restrict__ cnt,
                                int* __restrict__ ovf_cnt, int* __restrict__ bpad,
                                int* __restrict__ ovf, int N, int E) {
  __shared__ float s_x[128 * G0_PAD];
  int t = threadIdx.x;

  // ---- scatter share (grid-stride, all blocks); buckets hold src ids directly ----
  for (int e = blockIdx.x * blockDim.x + t; e < E; e += gridDim.x * blockDim.x) {
    int d = dst[e];
    int pos = atomicAdd(&cnt[(size_t)d * CSTR], 1);
    if (pos < CAPB) bpad[(size_t)d * CAPB + pos] = src[e];
    else { int op = atomicAdd(ovf_cnt, 1); ovf[op] = e; }
  }

  // ---- gemm0 tile (block-uniform branch) ----
  if (blockIdx.x >= (N + G0_ROWS - 1) / G0_ROWS) return;
  int w = t >> 6, l = t & 63;
  int row0 = blockIdx.x * G0_ROWS;
  {
    int row = row0 + l; if (row >= N) row = N - 1;
    const float* xp = x + (size_t)row * 128 + w * 32;
#pragma unroll
    for (int j = 0; j < 8; ++j) {
      float4 v = *(const float4*)(xp + 4 * j);
      int k = w * 32 + 4 * j;
      s_x[(k + 0) * G0_PAD + l] = v.x;
      s_x[(k + 1) * G0_PAD + l] = v.y;
      s_x[(k + 2) * G0_PAD + l] = v.z;
      s_x[(k + 3) * G0_PAD + l] = v.w;
    }
  }
  __syncthreads();

  float4 acc[16];
#pragma unroll
  for (int r = 0; r < 16; ++r) acc[r] = make_float4(0.f, 0.f, 0.f, 0.f);

  const float* wp = W0 + 4 * l;
  int rbase = w * 16;
  for (int k = 0; k < 128; ++k) {
    float4 w4 = *(const float4*)(wp + (size_t)k * 256);
    const float* xk = &s_x[k * G0_PAD + rbase];
    float xv[16];
    *(float4*)&xv[0]  = *(const float4*)(xk);
    *(float4*)&xv[4]  = *(const float4*)(xk + 4);
    *(float4*)&xv[8]  = *(const float4*)(xk + 8);
    *(float4*)&xv[12] = *(const float4*)(xk + 12);
#pragma unroll
    for (int r = 0; r < 16; ++r) {
      acc[r].x = fmaf(xv[r], w4.x, acc[r].x);
      acc[r].y = fmaf(xv[r], w4.y, acc[r].y);
      acc[r].z = fmaf(xv[r], w4.z, acc[r].z);
      acc[r].w = fmaf(xv[r], w4.w, acc[r].w);
    }
  }

  int hh = l >> 3;
  float4 al4 = *(const float4*)(al + 4 * l);
  float4 ar4 = *(const float4*)(ar + 4 * l);
#pragma unroll
  for (int r = 0; r < 16; ++r) {
    int row = row0 + rbase + r;
    float4 f = acc[r];
    if (row < N) *(float4*)(f0 + (size_t)row * 256 + 4 * l) = f;
    float pl = fmaf(f.x, al4.x, fmaf(f.y, al4.y, fmaf(f.z, al4.z, f.w * al4.w)));
    float pr = fmaf(f.x, ar4.x, fmaf(f.y, ar4.y, fmaf(f.z, ar4.z, f.w * ar4.w)));
#pragma unroll
    for (int off = 4; off >= 1; off >>= 1) {
      pl += __shfl_xor(pl, off, 64);
      pr += __shfl_xor(pr, off, 64);
    }
    if ((l & 7) == 0 && row < N) {
      el[row * 8 + hh] = pl;
      er[row * 8 + hh] = pr;
    }
  }
}

// ---------------- fused edge kernel layer 0 + layer-1 projection ----------------
__global__ void k_fused0(const float* __restrict__ el, const float* __restrict__ er,
                         const float* __restrict__ f0, const int* __restrict__ cnt,
                         const int* __restrict__ ovf_cnt, const int* __restrict__ bpad,
                         const int* __restrict__ ovf, const int* __restrict__ dstp,
                         const int* __restrict__ src, const float* __restrict__ b0,
                         const float* __restrict__ W1, const float* __restrict__ al1,
                         const float* __restrict__ ar1, float* __restrict__ f1,
                         float* __restrict__ el1, float* __restrict__ er1, int N) {
  __shared__ float s_w[8][SWS];
  __shared__ int s_src[CAP0];
  __shared__ float s_red[4][256];
  __shared__ float s_hrow[256];
  __shared__ float s_p[8][32];
  __shared__ int s_deg;
  int n = blockIdx.x;
  int t = threadIdx.x;
  int h = t >> 5, lane = t & 31;

  // ---- phase 0: stage src ids ----
  int cn = cnt[(size_t)n * CSTR];
  int degb = cn < CAPB ? cn : CAPB;
  for (int i = t; i < degb; i += 256)
    s_src[i] = bpad[(size_t)n * CAPB + i];
  if (t == 0) {
    int d = degb;
    int ovl = ovf_cnt[0];                 // 0 in practice
    for (int j = 0; j < ovl && d < CAP0; ++j) {
      int e = ovf[j];
      if (dstp[e] == n) s_src[d++] = src[e];
    }
    s_deg = d;
  }
  __syncthreads();
  int deg = s_deg;
  float er_h = er[n * 8 + h];

  // ---- phase 1: scores + segment softmax into s_w ----
  float m = -INFINITY;
  for (int i = lane; i < deg; i += 32) {
    float v = el[s_src[i] * 8 + h] + er_h;
    v = v >= 0.f ? v : 0.2f * v;
    s_w[h][i] = v;
    m = fmaxf(m, v);
  }
#pragma unroll
  for (int off = 16; off >= 1; off >>= 1) m = fmaxf(m, __shfl_xor(m, off, 32));
  float sum = 0.f;
  for (int i = lane; i < deg; i += 32) {
    float a = expf(s_w[h][i] - m);
    s_w[h][i] = a;
    sum += a;
  }
#pragma unroll
  for (int off = 16; off >= 1; off >>= 1) sum += __shfl_xor(sum, off, 32);
  for (int i = lane; i < deg; i += 32) s_w[h][i] /= sum;   // IEEE div as reference
  __syncthreads();

  // ---- phase 2: gather. wave w handles edges w, w+4, ...; 4 rows in flight ----
  int w = t >> 6;
  int l = t & 63;
  int hh = l >> 3;
  float4 a4 = make_float4(0.f, 0.f, 0.f, 0.f);
  int i = w;
  for (; i + 12 < deg; i += 16) {
    float a0 = s_w[hh][i];
    float a1 = s_w[hh][i + 4];
    float a2 = s_w[hh][i + 8];
    float a3 = s_w[hh][i + 12];
    float4 v0 = ((const float4*)(f0 + (size_t)s_src[i] * 256))[l];
    float4 v1 = ((const float4*)(f0 + (size_t)s_src[i + 4] * 256))[l];
    float4 v2 = ((const float4*)(f0 + (size_t)s_src[i + 8] * 256))[l];
    float4 v3 = ((const float4*)(f0 + (size_t)s_src[i + 12] * 256))[l];
    a4.x = fmaf(a0, v0.x, a4.x); a4.y = fmaf(a0, v0.y, a4.y);
    a4.z = fmaf(a0, v0.z, a4.z); a4.w = fmaf(a0, v0.w, a4.w);
    a4.x = fmaf(a1, v1.x, a4.x); a4.y = fmaf(a1, v1.y, a4.y);
    a4.z = fmaf(a1, v1.z, a4.z); a4.w = fmaf(a1, v1.w, a4.w);
    a4.x = fmaf(a2, v2.x, a4.x); a4.y = fmaf(a2, v2.y, a4.y);
    a4.z = fmaf(a2, v2.z, a4.z); a4.w = fmaf(a2, v2.w, a4.w);
    a4.x = fmaf(a3, v3.x, a4.x); a4.y = fmaf(a3, v3.y, a4.y);
    a4.z = fmaf(a3, v3.z, a4.z); a4.w = fmaf(a3, v3.w, a4.w);
  }
  for (; i < deg; i += 4) {
    float a0 = s_w[hh][i];
    float4 v0 = ((const float4*)(f0 + (size_t)s_src[i] * 256))[l];
    a4.x = fmaf(a0, v0.x, a4.x); a4.y = fmaf(a0, v0.y, a4.y);
    a4.z = fmaf(a0, v0.z, a4.z); a4.w = fmaf(a0, v0.w, a4.w);
  }
  ((float4*)s_red[w])[l] = a4;
  __syncthreads();
  float o = ((s_red[0][t] + s_red[1][t]) + (s_red[2][t] + s_red[3][t])) + b0[t];

  // ---- epilogue: h-row in LDS; f1 = h @ W1; el1/er1 dots ----
  o = o > 0.f ? o : expm1f(o);   // jax.nn.elu
  s_hrow[t] = o;
  __syncthreads();
  {
    int col = t & 31, g = t >> 5;
    const float* hp = &s_hrow[g * 32];
    const float* wp2 = W1 + (size_t)(g * 32) * 32 + col;
    float p = 0.f;
#pragma unroll 8
    for (int j = 0; j < 32; ++j)
      p = fmaf(hp[j], wp2[j * 32], p);
    s_p[g][col] = p;
  }
  __syncthreads();
  if (t < 32) {
    float f = 0.f;
#pragma unroll
    for (int g = 0; g < 8; ++g) f += s_p[g][t];
    float pl = f * al1[t];
    float pr = f * ar1[t];
#pragma unroll
    for (int off = 16; off >= 1; off >>= 1) {
      pl += __shfl_xor(pl, off, 32);
      pr += __shfl_xor(pr, off, 32);
    }
    f1[(size_t)n * 32 + t] = f;
    if (t == 0) { el1[n] = pl; er1[n] = pr; }
  }
}

// ---------------- fused edge kernel layer 1 (H=1, D=32) ----------------
__global__ void k_fused1(const float* __restrict__ el, const float* __restrict__ er,
                         const float* __restrict__ f1, const int* __restrict__ cnt,
                         const int* __restrict__ ovf_cnt, const int* __restrict__ bpad,
                         const int* __restrict__ ovf, const int* __restrict__ dstp,
                         const int* __restrict__ src, const float* __restrict__ b1,
                         float* __restrict__ h1, int N) {
  __shared__ float s_w[4][CAP0];
  __shared__ int s_s[4][CAP0];
  int g = threadIdx.x >> 6;
  int lane = threadIdx.x & 63;
  int n = blockIdx.x * 4 + g;
  int nn = n < N ? n : N - 1;
  int cn = cnt[(size_t)nn * CSTR];
  int degb = cn < CAPB ? cn : CAPB;
  float er_n = er[nn];

  for (int i = lane; i < degb; i += 64)
    s_s[g][i] = bpad[(size_t)nn * CAPB + i];
  int deg = degb;
  {
    int ovl = ovf_cnt[0];
    if (ovl) {                            // never in practice
      if (lane == 0) {
        int d = degb;
        for (int j = 0; j < ovl && d < CAP0; ++j) {
          int e = ovf[j];
          if (dstp[e] == nn) s_s[g][d++] = src[e];
        }
        s_w[g][0] = __int_as_float(d);    // stash
      }
      deg = __float_as_int(__shfl(s_w[g][0], 0, 64));
    }
  }

  float m = -INFINITY;
  for (int i = lane; i < deg; i += 64) {
    float v = el[s_s[g][i]] + er_n;
    v = v >= 0.f ? v : 0.2f * v;
    s_w[g][i] = v;
    m = fmaxf(m, v);
  }
#pragma unroll
  for (int off = 32; off >= 1; off >>= 1) m = fmaxf(m, __shfl_xor(m, off, 64));
  float sum = 0.f;
  for (int i = lane; i < deg; i += 64) {
    float a = expf(s_w[g][i] - m);
    s_w[g][i] = a;
    sum += a;
  }
#pragma unroll
  for (int off = 32; off >= 1; off >>= 1) sum += __shfl_xor(sum, off, 64);
  for (int i = lane; i < deg; i += 64) s_w[g][i] /= sum;

  int es = lane >> 3, q = lane & 7;
  float4 a4 = make_float4(0.f, 0.f, 0.f, 0.f);
  int i = es;
  for (; i + 8 < deg; i += 16) {           // 2 rows in flight
    float a = s_w[g][i];
    float b = s_w[g][i + 8];
    float4 v0 = ((const float4*)(f1 + (size_t)s_s[g][i] * 32))[q];
    float4 v1 = ((const float4*)(f1 + (size_t)s_s[g][i + 8] * 32))[q];
    a4.x = fmaf(a, v0.x, a4.x); a4.y = fmaf(a, v0.y, a4.y);
    a4.z = fmaf(a, v0.z, a4.z); a4.w = fmaf(a, v0.w, a4.w);
    a4.x = fmaf(b, v1.x, a4.x); a4.y = fmaf(b, v1.y, a4.y);
    a4.z = fmaf(b, v1.z, a4.z); a4.w = fmaf(b, v1.w, a4.w);
  }
  for (; i < deg; i += 8) {
    float a = s_w[g][i];
    float4 v = ((const float4*)(f1 + (size_t)s_s[g][i] * 32))[q];
    a4.x = fmaf(a, v.x, a4.x); a4.y = fmaf(a, v.y, a4.y);
    a4.z = fmaf(a, v.z, a4.z); a4.w = fmaf(a, v.w, a4.w);
  }
#pragma unroll
  for (int off = 8; off <= 32; off <<= 1) {
    a4.x += __shfl_xor(a4.x, off, 64);
    a4.y += __shfl_xor(a4.y, off, 64);
    a4.z += __shfl_xor(a4.z, off, 64);
    a4.w += __shfl_xor(a4.w, off, 64);
  }
  if (lane < 8 && n < N) {
    float4 b = *(const float4*)(b1 + lane * 4);
    a4.x += b.x; a4.y += b.y; a4.z += b.z; a4.w += b.w;
    ((float4*)(h1 + (size_t)n * 32))[lane] = a4;
  }
}

// ---------------- predictor (f64 acc — negligible cost, keeps margin) ----------------
__global__ void k_pred(const float* __restrict__ h1, const float* __restrict__ P1,
                       const float* __restrict__ pb1, const float* __restrict__ P2,
                       const float* __restrict__ pb2, const float* __restrict__ P3,
                       const float* __restrict__ pb3, float* __restrict__ out,
                       int num_edge, int total) {
  int t = threadIdx.x;
  int lane = t & 31, grp = t >> 5;
  int k = blockIdx.x * 8 + grp;
  int kk = k < total ? k : 0;
  float z;
  if (kk < num_edge) {
    z = h1[(size_t)kk * 32 + lane] * h1[(size_t)(kk + num_edge) * 32 + lane];
  } else {
    int i = kk - num_edge;
    z = h1[(size_t)(i % num_edge) * 32 + lane] * h1[(size_t)(2 * num_edge + i) * 32 + lane];
  }
  double a1 = 0;
#pragma unroll
  for (int d = 0; d < 32; ++d)
    a1 += (double)__shfl(z, d, 32) * (double)P1[d * 32 + lane];
  float t1 = (float)(a1 + (double)pb1[lane]);
  t1 = t1 > 0.f ? t1 : 0.f;
  double a2 = 0;
#pragma unroll
  for (int d = 0; d < 32; ++d)
    a2 += (double)__shfl(t1, d, 32) * (double)P2[d * 32 + lane];
  float t2 = (float)(a2 + (double)pb2[lane]);
  t2 = t2 > 0.f ? t2 : 0.f;
  double a3 = (double)t2 * (double)P3[lane];
#pragma unroll
  for (int off = 16; off >= 1; off >>= 1) a3 += __shfl_xor(a3, off, 64);
  if (lane == 0 && k < total) out[k] = (float)(a3 + (double)pb3[0]);
}

extern "C" void kernel_launch(void* const* d_in, const int* in_sizes, int n_in,
                              void* d_out, int out_size, void* d_ws, size_t ws_size,
                              hipStream_t stream) {
  const float* x   = (const float*)d_in[0];
  const int*   src = (const int*)d_in[1];
  const int*   dst = (const int*)d_in[2];
  const float* W0  = (const float*)d_in[4];
  const float* al0 = (const float*)d_in[5];
  const float* ar0 = (const float*)d_in[6];
  const float* b0  = (const float*)d_in[7];
  const float* W1  = (const float*)d_in[8];
  const float* al1 = (const float*)d_in[9];
  const float* ar1 = (const float*)d_in[10];
  const float* b1  = (const float*)d_in[11];
  const float* P1  = (const float*)d_in[12];
  const float* pb1 = (const float*)d_in[13];
  const float* P2  = (const float*)d_in[14];
  const float* pb2 = (const float*)d_in[15];
  const float* P3  = (const float*)d_in[16];
  const float* pb3 = (const float*)d_in[17];

  int N = in_sizes[0] / 128;
  int E = in_sizes[1];
  int num_edge = N - out_size;   // N=(2+r)*ne, out=(1+r)*ne

  size_t off = 0;
  auto alloc = [&](size_t bytes) -> void* {
    void* p = (char*)d_ws + off;
    off += (bytes + 255) & ~(size_t)255;
    return p;
  };
  float* f0   = (float*)alloc((size_t)N * 256 * 4);
  float* f1   = (float*)alloc((size_t)N * 32 * 4);
  float* h1   = (float*)alloc((size_t)N * 32 * 4);
  float* el   = (float*)alloc((size_t)N * 8 * 4);
  float* er   = (float*)alloc((size_t)N * 8 * 4);
  float* el1  = (float*)alloc((size_t)N * 4);
  float* er1  = (float*)alloc((size_t)N * 4);
  int*   cnt  = (int*)alloc(((size_t)N * CSTR + 1) * 4);  // 1 counter/64B line; [N*CSTR] = ovf counter
  int*   bpad = (int*)alloc((size_t)N * CAPB * 4);
  int*   ovf  = (int*)alloc((size_t)E * 4);
  if (off > ws_size) return;
  int* ovf_cnt = cnt + (size_t)N * CSTR;

  hipMemsetAsync(cnt, 0, ((size_t)N * CSTR + 1) * 4, stream);
  k_gemm0_scatter<<<1024, 256, 0, stream>>>(x, W0, al0, ar0, dst, src,
                                            f0, el, er, cnt, ovf_cnt, bpad, ovf, N, E);
  k_fused0<<<N, 256, 0, stream>>>(el, er, f0, cnt, ovf_cnt, bpad, ovf, dst, src, b0,
                                  W1, al1, ar1, f1, el1, er1, N);
  k_fused1<<<(N + 3) / 4, 256, 0, stream>>>(el1, er1, f1, cnt, ovf_cnt, bpad, ovf, dst,
                                            src, b1, h1, N);
  k_pred<<<(out_size + 7) / 8, 256, 0, stream>>>(h1, P1, pb1, P2, pb2, P3, pb3,
                                                 (float*)d_out, num_edge, out_size);
}

// Round 16
// 387.648 us; speedup vs baseline: 1.0768x; 1.0768x over previous
//
#include <hip/hip_runtime.h>
#include <hip/hip_fp16.h>
#include <cmath>

#define CAPB 64    // padded bucket capacity; deg~Poisson(16), P(>64)~1e-21; overflow list for safety
#define CAP0 192   // max staged degree in fused kernels (bucket + appended overflow)
#define SWS  196   // s_w row stride: 196%32=4 -> 8 head-rows hit distinct banks
#define G0_ROWS 64
#define G0_PAD 68

// ---------------- merged: edge scatter (all blocks) + GEMM0 tile (first blocks) ----------
// f0 gather table stored in FP16 (halves the 8xXCD L2-fill traffic of the random
// gather). el/er computed from fp32 accumulators BEFORE rounding.
__global__ void k_gemm0_scatter(const float* __restrict__ x, const float* __restrict__ W0,
                                const float* __restrict__ al, const float* __restrict__ ar,
                                const int* __restrict__ dst, const int* __restrict__ src,
                                unsigned short* __restrict__ f0h, float* __restrict__ el,
                                float* __restrict__ er, int* __restrict__ cnt,
                                int* __restrict__ ovf_cnt, int* __restrict__ bpad,
                                int* __restrict__ ovf, int N, int E) {
  __shared__ float s_x[128 * G0_PAD];
  int t = threadIdx.x;

  // ---- scatter share (grid-stride, all blocks); buckets hold src ids directly ----
  for (int e = blockIdx.x * blockDim.x + t; e < E; e += gridDim.x * blockDim.x) {
    int d = dst[e];
    int pos = atomicAdd(&cnt[d], 1);
    if (pos < CAPB) bpad[(size_t)d * CAPB + pos] = src[e];
    else { int op = atomicAdd(ovf_cnt, 1); ovf[op] = e; }
  }

  // ---- gemm0 tile (block-uniform branch) ----
  if (blockIdx.x >= (N + G0_ROWS - 1) / G0_ROWS) return;
  int w = t >> 6, l = t & 63;
  int row0 = blockIdx.x * G0_ROWS;
  {
    int row = row0 + l; if (row >= N) row = N - 1;
    const float* xp = x + (size_t)row * 128 + w * 32;
#pragma unroll
    for (int j = 0; j < 8; ++j) {
      float4 v = *(const float4*)(xp + 4 * j);
      int k = w * 32 + 4 * j;
      s_x[(k + 0) * G0_PAD + l] = v.x;
      s_x[(k + 1) * G0_PAD + l] = v.y;
      s_x[(k + 2) * G0_PAD + l] = v.z;
      s_x[(k + 3) * G0_PAD + l] = v.w;
    }
  }
  __syncthreads();

  float4 acc[16];
#pragma unroll
  for (int r = 0; r < 16; ++r) acc[r] = make_float4(0.f, 0.f, 0.f, 0.f);

  const float* wp = W0 + 4 * l;
  int rbase = w * 16;
  for (int k = 0; k < 128; ++k) {
    float4 w4 = *(const float4*)(wp + (size_t)k * 256);
    const float* xk = &s_x[k * G0_PAD + rbase];
    float xv[16];
    *(float4*)&xv[0]  = *(const float4*)(xk);
    *(float4*)&xv[4]  = *(const float4*)(xk + 4);
    *(float4*)&xv[8]  = *(const float4*)(xk + 8);
    *(float4*)&xv[12] = *(const float4*)(xk + 12);
#pragma unroll
    for (int r = 0; r < 16; ++r) {
      acc[r].x = fmaf(xv[r], w4.x, acc[r].x);
      acc[r].y = fmaf(xv[r], w4.y, acc[r].y);
      acc[r].z = fmaf(xv[r], w4.z, acc[r].z);
      acc[r].w = fmaf(xv[r], w4.w, acc[r].w);
    }
  }

  int hh = l >> 3;
  float4 al4 = *(const float4*)(al + 4 * l);
  float4 ar4 = *(const float4*)(ar + 4 * l);
#pragma unroll
  for (int r = 0; r < 16; ++r) {
    int row = row0 + rbase + r;
    float4 f = acc[r];
    if (row < N) {
      ushort4 h4;
      h4.x = __half_as_ushort(__float2half_rn(f.x));
      h4.y = __half_as_ushort(__float2half_rn(f.y));
      h4.z = __half_as_ushort(__float2half_rn(f.z));
      h4.w = __half_as_ushort(__float2half_rn(f.w));
      *(ushort4*)(f0h + (size_t)row * 256 + 4 * l) = h4;
    }
    float pl = fmaf(f.x, al4.x, fmaf(f.y, al4.y, fmaf(f.z, al4.z, f.w * al4.w)));
    float pr = fmaf(f.x, ar4.x, fmaf(f.y, ar4.y, fmaf(f.z, ar4.z, f.w * ar4.w)));
#pragma unroll
    for (int off = 4; off >= 1; off >>= 1) {
      pl += __shfl_xor(pl, off, 64);
      pr += __shfl_xor(pr, off, 64);
    }
    if ((l & 7) == 0 && row < N) {
      el[row * 8 + hh] = pl;
      er[row * 8 + hh] = pr;
    }
  }
}

// ---------------- fused edge kernel layer 0 + layer-1 projection ----------------
// Phase 2 gathers FP16 rows (8 B/lane dwordx2), converts in-register.
__global__ void k_fused0(const float* __restrict__ el, const float* __restrict__ er,
                         const unsigned short* __restrict__ f0h, const int* __restrict__ cnt,
                         const int* __restrict__ ovf_cnt, const int* __restrict__ bpad,
                         const int* __restrict__ ovf, const int* __restrict__ dstp,
                         const int* __restrict__ src, const float* __restrict__ b0,
                         const float* __restrict__ W1, const float* __restrict__ al1,
                         const float* __restrict__ ar1, float* __restrict__ f1,
                         float* __restrict__ el1, float* __restrict__ er1, int N) {
  __shared__ float s_w[8][SWS];
  __shared__ int s_src[CAP0];
  __shared__ float s_red[4][256];
  __shared__ float s_hrow[256];
  __shared__ float s_p[8][32];
  __shared__ int s_deg;
  int n = blockIdx.x;
  int t = threadIdx.x;
  int h = t >> 5, lane = t & 31;

  // ---- phase 0: stage src ids ----
  int cn = cnt[n];
  int degb = cn < CAPB ? cn : CAPB;
  for (int i = t; i < degb; i += 256)
    s_src[i] = bpad[(size_t)n * CAPB + i];
  if (t == 0) {
    int d = degb;
    int ovl = ovf_cnt[0];                 // 0 in practice
    for (int j = 0; j < ovl && d < CAP0; ++j) {
      int e = ovf[j];
      if (dstp[e] == n) s_src[d++] = src[e];
    }
    s_deg = d;
  }
  __syncthreads();
  int deg = s_deg;
  float er_h = er[n * 8 + h];

  // ---- phase 1: scores + segment softmax into s_w ----
  float m = -INFINITY;
  for (int i = lane; i < deg; i += 32) {
    float v = el[s_src[i] * 8 + h] + er_h;
    v = v >= 0.f ? v : 0.2f * v;
    s_w[h][i] = v;
    m = fmaxf(m, v);
  }
#pragma unroll
  for (int off = 16; off >= 1; off >>= 1) m = fmaxf(m, __shfl_xor(m, off, 32));
  float sum = 0.f;
  for (int i = lane; i < deg; i += 32) {
    float a = expf(s_w[h][i] - m);
    s_w[h][i] = a;
    sum += a;
  }
#pragma unroll
  for (int off = 16; off >= 1; off >>= 1) sum += __shfl_xor(sum, off, 32);
  for (int i = lane; i < deg; i += 32) s_w[h][i] /= sum;   // IEEE div as reference
  __syncthreads();

  // ---- phase 2: fp16 gather. wave w handles edges w, w+4, ...; 2 rows in flight ----
  int w = t >> 6;
  int l = t & 63;
  int hh = l >> 3;
  float4 a4 = make_float4(0.f, 0.f, 0.f, 0.f);
  int i = w;
  for (; i + 4 < deg; i += 8) {
    float a0 = s_w[hh][i];
    float a1 = s_w[hh][i + 4];
    ushort4 u0 = ((const ushort4*)(f0h + (size_t)s_src[i] * 256))[l];
    ushort4 u1 = ((const ushort4*)(f0h + (size_t)s_src[i + 4] * 256))[l];
    float4 v0, v1;
    v0.x = __half2float(__ushort_as_half(u0.x));
    v0.y = __half2float(__ushort_as_half(u0.y));
    v0.z = __half2float(__ushort_as_half(u0.z));
    v0.w = __half2float(__ushort_as_half(u0.w));
    v1.x = __half2float(__ushort_as_half(u1.x));
    v1.y = __half2float(__ushort_as_half(u1.y));
    v1.z = __half2float(__ushort_as_half(u1.z));
    v1.w = __half2float(__ushort_as_half(u1.w));
    a4.x = fmaf(a0, v0.x, a4.x); a4.y = fmaf(a0, v0.y, a4.y);
    a4.z = fmaf(a0, v0.z, a4.z); a4.w = fmaf(a0, v0.w, a4.w);
    a4.x = fmaf(a1, v1.x, a4.x); a4.y = fmaf(a1, v1.y, a4.y);
    a4.z = fmaf(a1, v1.z, a4.z); a4.w = fmaf(a1, v1.w, a4.w);
  }
  if (i < deg) {
    float a0 = s_w[hh][i];
    ushort4 u0 = ((const ushort4*)(f0h + (size_t)s_src[i] * 256))[l];
    float4 v0;
    v0.x = __half2float(__ushort_as_half(u0.x));
    v0.y = __half2float(__ushort_as_half(u0.y));
    v0.z = __half2float(__ushort_as_half(u0.z));
    v0.w = __half2float(__ushort_as_half(u0.w));
    a4.x = fmaf(a0, v0.x, a4.x); a4.y = fmaf(a0, v0.y, a4.y);
    a4.z = fmaf(a0, v0.z, a4.z); a4.w = fmaf(a0, v0.w, a4.w);
  }
  ((float4*)s_red[w])[l] = a4;
  __syncthreads();
  float o = ((s_red[0][t] + s_red[1][t]) + (s_red[2][t] + s_red[3][t])) + b0[t];

  // ---- epilogue: h-row in LDS; f1 = h @ W1; el1/er1 dots ----
  o = o > 0.f ? o : expm1f(o);   // jax.nn.elu
  s_hrow[t] = o;
  __syncthreads();
  {
    int col = t & 31, g = t >> 5;
    const float* hp = &s_hrow[g * 32];
    const float* wp2 = W1 + (size_t)(g * 32) * 32 + col;
    float p = 0.f;
#pragma unroll 8
    for (int j = 0; j < 32; ++j)
      p = fmaf(hp[j], wp2[j * 32], p);
    s_p[g][col] = p;
  }
  __syncthreads();
  if (t < 32) {
    float f = 0.f;
#pragma unroll
    for (int g = 0; g < 8; ++g) f += s_p[g][t];
    float pl = f * al1[t];
    float pr = f * ar1[t];
#pragma unroll
    for (int off = 16; off >= 1; off >>= 1) {
      pl += __shfl_xor(pl, off, 32);
      pr += __shfl_xor(pr, off, 32);
    }
    f1[(size_t)n * 32 + t] = f;
    if (t == 0) { el1[n] = pl; er1[n] = pr; }
  }
}

// ---------------- fused edge kernel layer 1 (H=1, D=32, fp32 f1) ----------------
__global__ void k_fused1(const float* __restrict__ el, const float* __restrict__ er,
                         const float* __restrict__ f1, const int* __restrict__ cnt,
                         const int* __restrict__ ovf_cnt, const int* __restrict__ bpad,
                         const int* __restrict__ ovf, const int* __restrict__ dstp,
                         const int* __restrict__ src, const float* __restrict__ b1,
                         float* __restrict__ h1, int N) {
  __shared__ float s_w[4][CAP0];
  __shared__ int s_s[4][CAP0];
  int g = threadIdx.x >> 6;
  int lane = threadIdx.x & 63;
  int n = blockIdx.x * 4 + g;
  int nn = n < N ? n : N - 1;
  int cn = cnt[nn];
  int degb = cn < CAPB ? cn : CAPB;
  float er_n = er[nn];

  for (int i = lane; i < degb; i += 64)
    s_s[g][i] = bpad[(size_t)nn * CAPB + i];
  int deg = degb;
  {
    int ovl = ovf_cnt[0];
    if (ovl) {                            // never in practice
      if (lane == 0) {
        int d = degb;
        for (int j = 0; j < ovl && d < CAP0; ++j) {
          int e = ovf[j];
          if (dstp[e] == nn) s_s[g][d++] = src[e];
        }
        s_w[g][0] = __int_as_float(d);    // stash
      }
      deg = __float_as_int(__shfl(s_w[g][0], 0, 64));
    }
  }

  float m = -INFINITY;
  for (int i = lane; i < deg; i += 64) {
    float v = el[s_s[g][i]] + er_n;
    v = v >= 0.f ? v : 0.2f * v;
    s_w[g][i] = v;
    m = fmaxf(m, v);
  }
#pragma unroll
  for (int off = 32; off >= 1; off >>= 1) m = fmaxf(m, __shfl_xor(m, off, 64));
  float sum = 0.f;
  for (int i = lane; i < deg; i += 64) {
    float a = expf(s_w[g][i] - m);
    s_w[g][i] = a;
    sum += a;
  }
#pragma unroll
  for (int off = 32; off >= 1; off >>= 1) sum += __shfl_xor(sum, off, 64);
  for (int i = lane; i < deg; i += 64) s_w[g][i] /= sum;

  int es = lane >> 3, q = lane & 7;
  float4 a4 = make_float4(0.f, 0.f, 0.f, 0.f);
  int i = es;
  for (; i + 8 < deg; i += 16) {           // 2 rows in flight
    float a = s_w[g][i];
    float b = s_w[g][i + 8];
    float4 v0 = ((const float4*)(f1 + (size_t)s_s[g][i] * 32))[q];
    float4 v1 = ((const float4*)(f1 + (size_t)s_s[g][i + 8] * 32))[q];
    a4.x = fmaf(a, v0.x, a4.x); a4.y = fmaf(a, v0.y, a4.y);
    a4.z = fmaf(a, v0.z, a4.z); a4.w = fmaf(a, v0.w, a4.w);
    a4.x = fmaf(b, v1.x, a4.x); a4.y = fmaf(b, v1.y, a4.y);
    a4.z = fmaf(b, v1.z, a4.z); a4.w = fmaf(b, v1.w, a4.w);
  }
  for (; i < deg; i += 8) {
    float a = s_w[g][i];
    float4 v = ((const float4*)(f1 + (size_t)s_s[g][i] * 32))[q];
    a4.x = fmaf(a, v.x, a4.x); a4.y = fmaf(a, v.y, a4.y);
    a4.z = fmaf(a, v.z, a4.z); a4.w = fmaf(a, v.w, a4.w);
  }
#pragma unroll
  for (int off = 8; off <= 32; off <<= 1) {
    a4.x += __shfl_xor(a4.x, off, 64);
    a4.y += __shfl_xor(a4.y, off, 64);
    a4.z += __shfl_xor(a4.z, off, 64);
    a4.w += __shfl_xor(a4.w, off, 64);
  }
  if (lane < 8 && n < N) {
    float4 b = *(const float4*)(b1 + lane * 4);
    a4.x += b.x; a4.y += b.y; a4.z += b.z; a4.w += b.w;
    ((float4*)(h1 + (size_t)n * 32))[lane] = a4;
  }
}

// ---------------- predictor (f64 acc — negligible cost, keeps margin) ----------------
__global__ void k_pred(const float* __restrict__ h1, const float* __restrict__ P1,
                       const float* __restrict__ pb1, const float* __restrict__ P2,
                       const float* __restrict__ pb2, const float* __restrict__ P3,
                       const float* __restrict__ pb3, float* __restrict__ out,
                       int num_edge, int total) {
  int t = threadIdx.x;
  int lane = t & 31, grp = t >> 5;
  int k = blockIdx.x * 8 + grp;
  int kk = k < total ? k : 0;
  float z;
  if (kk < num_edge) {
    z = h1[(size_t)kk * 32 + lane] * h1[(size_t)(kk + num_edge) * 32 + lane];
  } else {
    int i = kk - num_edge;
    z = h1[(size_t)(i % num_edge) * 32 + lane] * h1[(size_t)(2 * num_edge + i) * 32 + lane];
  }
  double a1 = 0;
#pragma unroll
  for (int d = 0; d < 32; ++d)
    a1 += (double)__shfl(z, d, 32) * (double)P1[d * 32 + lane];
  float t1 = (float)(a1 + (double)pb1[lane]);
  t1 = t1 > 0.f ? t1 : 0.f;
  double a2 = 0;
#pragma unroll
  for (int d = 0; d < 32; ++d)
    a2 += (double)__shfl(t1, d, 32) * (double)P2[d * 32 + lane];
  float t2 = (float)(a2 + (double)pb2[lane]);
  t2 = t2 > 0.f ? t2 : 0.f;
  double a3 = (double)t2 * (double)P3[lane];
#pragma unroll
  for (int off = 16; off >= 1; off >>= 1) a3 += __shfl_xor(a3, off, 64);
  if (lane == 0 && k < total) out[k] = (float)(a3 + (double)pb3[0]);
}

extern "C" void kernel_launch(void* const* d_in, const int* in_sizes, int n_in,
                              void* d_out, int out_size, void* d_ws, size_t ws_size,
                              hipStream_t stream) {
  const float* x   = (const float*)d_in[0];
  const int*   src = (const int*)d_in[1];
  const int*   dst = (const int*)d_in[2];
  const float* W0  = (const float*)d_in[4];
  const float* al0 = (const float*)d_in[5];
  const float* ar0 = (const float*)d_in[6];
  const float* b0  = (const float*)d_in[7];
  const float* W1  = (const float*)d_in[8];
  const float* al1 = (const float*)d_in[9];
  const float* ar1 = (const float*)d_in[10];
  const float* b1  = (const float*)d_in[11];
  const float* P1  = (const float*)d_in[12];
  const float* pb1 = (const float*)d_in[13];
  const float* P2  = (const float*)d_in[14];
  const float* pb2 = (const float*)d_in[15];
  const float* P3  = (const float*)d_in[16];
  const float* pb3 = (const float*)d_in[17];

  int N = in_sizes[0] / 128;
  int E = in_sizes[1];
  int num_edge = N - out_size;   // N=(2+r)*ne, out=(1+r)*ne

  size_t off = 0;
  auto alloc = [&](size_t bytes) -> void* {
    void* p = (char*)d_ws + off;
    off += (bytes + 255) & ~(size_t)255;
    return p;
  };
  unsigned short* f0h = (unsigned short*)alloc((size_t)N * 256 * 2);   // fp16 gather table
  float* f1   = (float*)alloc((size_t)N * 32 * 4);
  float* h1   = (float*)alloc((size_t)N * 32 * 4);
  float* el   = (float*)alloc((size_t)N * 8 * 4);
  float* er   = (float*)alloc((size_t)N * 8 * 4);
  float* el1  = (float*)alloc((size_t)N * 4);
  float* er1  = (float*)alloc((size_t)N * 4);
  int*   cnt  = (int*)alloc((size_t)(N + 1) * 4);   // [N] = overflow counter
  int*   bpad = (int*)alloc((size_t)N * CAPB * 4);
  int*   ovf  = (int*)alloc((size_t)E * 4);
  if (off > ws_size) return;
  int* ovf_cnt = cnt + N;

  hipMemsetAsync(cnt, 0, (size_t)(N + 1) * 4, stream);
  k_gemm0_scatter<<<1024, 256, 0, stream>>>(x, W0, al0, ar0, dst, src,
                                            f0h, el, er, cnt, ovf_cnt, bpad, ovf, N, E);
  k_fused0<<<N, 256, 0, stream>>>(el, er, f0h, cnt, ovf_cnt, bpad, ovf, dst, src, b0,
                                  W1, al1, ar1, f1, el1, er1, N);
  k_fused1<<<(N + 3) / 4, 256, 0, stream>>>(el1, er1, f1, cnt, ovf_cnt, bpad, ovf, dst,
                                            src, b1, h1, N);
  k_pred<<<(out_size + 7) / 8, 256, 0, stream>>>(h1, P1, pb1, P2, pb2, P3, pb3,
                                                 (float*)d_out, num_edge, out_size);
}

// Round 17
// 341.184 us; speedup vs baseline: 1.2235x; 1.1362x over previous
//
#include <hip/hip_runtime.h>
#include <hip/hip_fp16.h>
#include <cmath>

#define CAPB 64    // padded bucket capacity; deg~Poisson(16), P(>64)~1e-21; overflow list for safety
#define CAP0 192   // max staged degree in fused kernels (bucket + appended overflow)
#define SWS  196   // s_w row stride: 196%32=4 -> 8 head-rows hit distinct banks
#define G0_ROWS 64
#define G0_PAD 68

// ---------------- merged kernel: gemm blocks OR scatter blocks (disjoint) ----------
// First ngemm blocks: GEMM0 tile only. Remaining blocks: edge scatter only.
// Both run concurrently in one dispatch; kernel boundary before fused0 guarantees
// bucket completeness. f0 stored FP16 (halves the 8xXCD gather fill traffic);
// el/er computed from fp32 accumulators BEFORE rounding.
__global__ void k_gemm0_scatter(const float* __restrict__ x, const float* __restrict__ W0,
                                const float* __restrict__ al, const float* __restrict__ ar,
                                const int* __restrict__ dst, const int* __restrict__ src,
                                unsigned short* __restrict__ f0h, float* __restrict__ el,
                                float* __restrict__ er, int* __restrict__ cnt,
                                int* __restrict__ ovf_cnt, int* __restrict__ bpad,
                                int* __restrict__ ovf, int N, int E, int ngemm) {
  __shared__ float s_x[128 * G0_PAD];
  int t = threadIdx.x;

  if (blockIdx.x >= ngemm) {
    // ---- scatter share (grid-stride over scatter blocks only) ----
    int nscat = gridDim.x - ngemm;
    for (int e = (blockIdx.x - ngemm) * blockDim.x + t; e < E; e += nscat * blockDim.x) {
      int d = dst[e];
      int pos = atomicAdd(&cnt[d], 1);
      if (pos < CAPB) bpad[(size_t)d * CAPB + pos] = src[e];
      else { int op = atomicAdd(ovf_cnt, 1); ovf[op] = e; }
    }
    return;
  }

  // ---- gemm0 tile ----
  int w = t >> 6, l = t & 63;
  int row0 = blockIdx.x * G0_ROWS;
  {
    int row = row0 + l; if (row >= N) row = N - 1;
    const float* xp = x + (size_t)row * 128 + w * 32;
#pragma unroll
    for (int j = 0; j < 8; ++j) {
      float4 v = *(const float4*)(xp + 4 * j);
      int k = w * 32 + 4 * j;
      s_x[(k + 0) * G0_PAD + l] = v.x;
      s_x[(k + 1) * G0_PAD + l] = v.y;
      s_x[(k + 2) * G0_PAD + l] = v.z;
      s_x[(k + 3) * G0_PAD + l] = v.w;
    }
  }
  __syncthreads();

  float4 acc[16];
#pragma unroll
  for (int r = 0; r < 16; ++r) acc[r] = make_float4(0.f, 0.f, 0.f, 0.f);

  const float* wp = W0 + 4 * l;
  int rbase = w * 16;
  for (int k = 0; k < 128; ++k) {
    float4 w4 = *(const float4*)(wp + (size_t)k * 256);
    const float* xk = &s_x[k * G0_PAD + rbase];
    float xv[16];
    *(float4*)&xv[0]  = *(const float4*)(xk);
    *(float4*)&xv[4]  = *(const float4*)(xk + 4);
    *(float4*)&xv[8]  = *(const float4*)(xk + 8);
    *(float4*)&xv[12] = *(const float4*)(xk + 12);
#pragma unroll
    for (int r = 0; r < 16; ++r) {
      acc[r].x = fmaf(xv[r], w4.x, acc[r].x);
      acc[r].y = fmaf(xv[r], w4.y, acc[r].y);
      acc[r].z = fmaf(xv[r], w4.z, acc[r].z);
      acc[r].w = fmaf(xv[r], w4.w, acc[r].w);
    }
  }

  int hh = l >> 3;
  float4 al4 = *(const float4*)(al + 4 * l);
  float4 ar4 = *(const float4*)(ar + 4 * l);
#pragma unroll
  for (int r = 0; r < 16; ++r) {
    int row = row0 + rbase + r;
    float4 f = acc[r];
    if (row < N) {
      ushort4 h4;
      h4.x = __half_as_ushort(__float2half_rn(f.x));
      h4.y = __half_as_ushort(__float2half_rn(f.y));
      h4.z = __half_as_ushort(__float2half_rn(f.z));
      h4.w = __half_as_ushort(__float2half_rn(f.w));
      *(ushort4*)(f0h + (size_t)row * 256 + 4 * l) = h4;
    }
    float pl = fmaf(f.x, al4.x, fmaf(f.y, al4.y, fmaf(f.z, al4.z, f.w * al4.w)));
    float pr = fmaf(f.x, ar4.x, fmaf(f.y, ar4.y, fmaf(f.z, ar4.z, f.w * ar4.w)));
#pragma unroll
    for (int off = 4; off >= 1; off >>= 1) {
      pl += __shfl_xor(pl, off, 64);
      pr += __shfl_xor(pr, off, 64);
    }
    if ((l & 7) == 0 && row < N) {
      el[row * 8 + hh] = pl;
      er[row * 8 + hh] = pr;
    }
  }
}

// ---------------- fused edge kernel layer 0 + layer-1 projection ----------------
__global__ void k_fused0(const float* __restrict__ el, const float* __restrict__ er,
                         const unsigned short* __restrict__ f0h, const int* __restrict__ cnt,
                         const int* __restrict__ ovf_cnt, const int* __restrict__ bpad,
                         const int* __restrict__ ovf, const int* __restrict__ dstp,
                         const int* __restrict__ src, const float* __restrict__ b0,
                         const float* __restrict__ W1, const float* __restrict__ al1,
                         const float* __restrict__ ar1, float* __restrict__ f1,
                         float* __restrict__ el1, float* __restrict__ er1, int N) {
  __shared__ float s_w[8][SWS];
  __shared__ int s_src[CAP0];
  __shared__ float s_red[4][256];
  __shared__ float s_hrow[256];
  __shared__ float s_p[8][32];
  __shared__ int s_deg;
  int n = blockIdx.x;
  int t = threadIdx.x;
  int h = t >> 5, lane = t & 31;

  // ---- phase 0: stage src ids ----
  int cn = cnt[n];
  int degb = cn < CAPB ? cn : CAPB;
  for (int i = t; i < degb; i += 256)
    s_src[i] = bpad[(size_t)n * CAPB + i];
  if (t == 0) {
    int d = degb;
    int ovl = ovf_cnt[0];                 // 0 in practice
    for (int j = 0; j < ovl && d < CAP0; ++j) {
      int e = ovf[j];
      if (dstp[e] == n) s_src[d++] = src[e];
    }
    s_deg = d;
  }
  __syncthreads();
  int deg = s_deg;
  float er_h = er[n * 8 + h];

  // ---- phase 1: scores + segment softmax into s_w ----
  float m = -INFINITY;
  for (int i = lane; i < deg; i += 32) {
    float v = el[s_src[i] * 8 + h] + er_h;
    v = v >= 0.f ? v : 0.2f * v;
    s_w[h][i] = v;
    m = fmaxf(m, v);
  }
#pragma unroll
  for (int off = 16; off >= 1; off >>= 1) m = fmaxf(m, __shfl_xor(m, off, 32));
  float sum = 0.f;
  for (int i = lane; i < deg; i += 32) {
    float a = expf(s_w[h][i] - m);
    s_w[h][i] = a;
    sum += a;
  }
#pragma unroll
  for (int off = 16; off >= 1; off >>= 1) sum += __shfl_xor(sum, off, 32);
  for (int i = lane; i < deg; i += 32) s_w[h][i] /= sum;   // IEEE div as reference
  __syncthreads();

  // ---- phase 2: fp16 gather. wave w handles edges w, w+4, ...; 4 rows in flight ----
  int w = t >> 6;
  int l = t & 63;
  int hh = l >> 3;
  float4 a4 = make_float4(0.f, 0.f, 0.f, 0.f);
  int i = w;
  for (; i + 12 < deg; i += 16) {
    float a0 = s_w[hh][i];
    float a1 = s_w[hh][i + 4];
    float a2 = s_w[hh][i + 8];
    float a3 = s_w[hh][i + 12];
    ushort4 u0 = ((const ushort4*)(f0h + (size_t)s_src[i] * 256))[l];
    ushort4 u1 = ((const ushort4*)(f0h + (size_t)s_src[i + 4] * 256))[l];
    ushort4 u2 = ((const ushort4*)(f0h + (size_t)s_src[i + 8] * 256))[l];
    ushort4 u3 = ((const ushort4*)(f0h + (size_t)s_src[i + 12] * 256))[l];
    a4.x = fmaf(a0, __half2float(__ushort_as_half(u0.x)), a4.x);
    a4.y = fmaf(a0, __half2float(__ushort_as_half(u0.y)), a4.y);
    a4.z = fmaf(a0, __half2float(__ushort_as_half(u0.z)), a4.z);
    a4.w = fmaf(a0, __half2float(__ushort_as_half(u0.w)), a4.w);
    a4.x = fmaf(a1, __half2float(__ushort_as_half(u1.x)), a4.x);
    a4.y = fmaf(a1, __half2float(__ushort_as_half(u1.y)), a4.y);
    a4.z = fmaf(a1, __half2float(__ushort_as_half(u1.z)), a4.z);
    a4.w = fmaf(a1, __half2float(__ushort_as_half(u1.w)), a4.w);
    a4.x = fmaf(a2, __half2float(__ushort_as_half(u2.x)), a4.x);
    a4.y = fmaf(a2, __half2float(__ushort_as_half(u2.y)), a4.y);
    a4.z = fmaf(a2, __half2float(__ushort_as_half(u2.z)), a4.z);
    a4.w = fmaf(a2, __half2float(__ushort_as_half(u2.w)), a4.w);
    a4.x = fmaf(a3, __half2float(__ushort_as_half(u3.x)), a4.x);
    a4.y = fmaf(a3, __half2float(__ushort_as_half(u3.y)), a4.y);
    a4.z = fmaf(a3, __half2float(__ushort_as_half(u3.z)), a4.z);
    a4.w = fmaf(a3, __half2float(__ushort_as_half(u3.w)), a4.w);
  }
  for (; i < deg; i += 4) {
    float a0 = s_w[hh][i];
    ushort4 u0 = ((const ushort4*)(f0h + (size_t)s_src[i] * 256))[l];
    a4.x = fmaf(a0, __half2float(__ushort_as_half(u0.x)), a4.x);
    a4.y = fmaf(a0, __half2float(__ushort_as_half(u0.y)), a4.y);
    a4.z = fmaf(a0, __half2float(__ushort_as_half(u0.z)), a4.z);
    a4.w = fmaf(a0, __half2float(__ushort_as_half(u0.w)), a4.w);
  }
  ((float4*)s_red[w])[l] = a4;
  __syncthreads();
  float o = ((s_red[0][t] + s_red[1][t]) + (s_red[2][t] + s_red[3][t])) + b0[t];

  // ---- epilogue: h-row in LDS; f1 = h @ W1 (b128 h loads); el1/er1 dots ----
  o = o > 0.f ? o : expm1f(o);   // jax.nn.elu
  s_hrow[t] = o;
  __syncthreads();
  {
    int col = t & 31, g = t >> 5;
    const float* hp = &s_hrow[g * 32];
    const float* wp2 = W1 + (size_t)(g * 32) * 32 + col;
    float p = 0.f;
#pragma unroll
    for (int j4 = 0; j4 < 8; ++j4) {
      float4 hv = *(const float4*)(hp + 4 * j4);          // ds_read_b128 broadcast
      const float* wq = wp2 + (size_t)(4 * j4) * 32;
      p = fmaf(hv.x, wq[0],  p);
      p = fmaf(hv.y, wq[32], p);
      p = fmaf(hv.z, wq[64], p);
      p = fmaf(hv.w, wq[96], p);
    }
    s_p[g][col] = p;
  }
  __syncthreads();
  if (t < 32) {
    float f = 0.f;
#pragma unroll
    for (int g = 0; g < 8; ++g) f += s_p[g][t];
    float pl = f * al1[t];
    float pr = f * ar1[t];
#pragma unroll
    for (int off = 16; off >= 1; off >>= 1) {
      pl += __shfl_xor(pl, off, 32);
      pr += __shfl_xor(pr, off, 32);
    }
    f1[(size_t)n * 32 + t] = f;
    if (t == 0) { el1[n] = pl; er1[n] = pr; }
  }
}

// ---------------- fused edge kernel layer 1 (H=1, D=32, fp32 f1) ----------------
__global__ void k_fused1(const float* __restrict__ el, const float* __restrict__ er,
                         const float* __restrict__ f1, const int* __restrict__ cnt,
                         const int* __restrict__ ovf_cnt, const int* __restrict__ bpad,
                         const int* __restrict__ ovf, const int* __restrict__ dstp,
                         const int* __restrict__ src, const float* __restrict__ b1,
                         float* __restrict__ h1, int N) {
  __shared__ float s_w[4][CAP0];
  __shared__ int s_s[4][CAP0];
  int g = threadIdx.x >> 6;
  int lane = threadIdx.x & 63;
  int n = blockIdx.x * 4 + g;
  int nn = n < N ? n : N - 1;
  int cn = cnt[nn];
  int degb = cn < CAPB ? cn : CAPB;
  float er_n = er[nn];

  for (int i = lane; i < degb; i += 64)
    s_s[g][i] = bpad[(size_t)nn * CAPB + i];
  int deg = degb;
  {
    int ovl = ovf_cnt[0];
    if (ovl) {                            // never in practice
      if (lane == 0) {
        int d = degb;
        for (int j = 0; j < ovl && d < CAP0; ++j) {
          int e = ovf[j];
          if (dstp[e] == nn) s_s[g][d++] = src[e];
        }
        s_w[g][0] = __int_as_float(d);    // stash
      }
      deg = __float_as_int(__shfl(s_w[g][0], 0, 64));
    }
  }

  float m = -INFINITY;
  for (int i = lane; i < deg; i += 64) {
    float v = el[s_s[g][i]] + er_n;
    v = v >= 0.f ? v : 0.2f * v;
    s_w[g][i] = v;
    m = fmaxf(m, v);
  }
#pragma unroll
  for (int off = 32; off >= 1; off >>= 1) m = fmaxf(m, __shfl_xor(m, off, 64));
  float sum = 0.f;
  for (int i = lane; i < deg; i += 64) {
    float a = expf(s_w[g][i] - m);
    s_w[g][i] = a;
    sum += a;
  }
#pragma unroll
  for (int off = 32; off >= 1; off >>= 1) sum += __shfl_xor(sum, off, 64);
  for (int i = lane; i < deg; i += 64) s_w[g][i] /= sum;

  int es = lane >> 3, q = lane & 7;
  float4 a4 = make_float4(0.f, 0.f, 0.f, 0.f);
  int i = es;
  for (; i + 8 < deg; i += 16) {           // 2 rows in flight
    float a = s_w[g][i];
    float b = s_w[g][i + 8];
    float4 v0 = ((const float4*)(f1 + (size_t)s_s[g][i] * 32))[q];
    float4 v1 = ((const float4*)(f1 + (size_t)s_s[g][i + 8] * 32))[q];
    a4.x = fmaf(a, v0.x, a4.x); a4.y = fmaf(a, v0.y, a4.y);
    a4.z = fmaf(a, v0.z, a4.z); a4.w = fmaf(a, v0.w, a4.w);
    a4.x = fmaf(b, v1.x, a4.x); a4.y = fmaf(b, v1.y, a4.y);
    a4.z = fmaf(b, v1.z, a4.z); a4.w = fmaf(b, v1.w, a4.w);
  }
  for (; i < deg; i += 8) {
    float a = s_w[g][i];
    float4 v = ((const float4*)(f1 + (size_t)s_s[g][i] * 32))[q];
    a4.x = fmaf(a, v.x, a4.x); a4.y = fmaf(a, v.y, a4.y);
    a4.z = fmaf(a, v.z, a4.z); a4.w = fmaf(a, v.w, a4.w);
  }
#pragma unroll
  for (int off = 8; off <= 32; off <<= 1) {
    a4.x += __shfl_xor(a4.x, off, 64);
    a4.y += __shfl_xor(a4.y, off, 64);
    a4.z += __shfl_xor(a4.z, off, 64);
    a4.w += __shfl_xor(a4.w, off, 64);
  }
  if (lane < 8 && n < N) {
    float4 b = *(const float4*)(b1 + lane * 4);
    a4.x += b.x; a4.y += b.y; a4.z += b.z; a4.w += b.w;
    ((float4*)(h1 + (size_t)n * 32))[lane] = a4;
  }
}

// ---------------- predictor (f64 acc — negligible cost, keeps margin) ----------------
__global__ void k_pred(const float* __restrict__ h1, const float* __restrict__ P1,
                       const float* __restrict__ pb1, const float* __restrict__ P2,
                       const float* __restrict__ pb2, const float* __restrict__ P3,
                       const float* __restrict__ pb3, float* __restrict__ out,
                       int num_edge, int total) {
  int t = threadIdx.x;
  int lane = t & 31, grp = t >> 5;
  int k = blockIdx.x * 8 + grp;
  int kk = k < total ? k : 0;
  float z;
  if (kk < num_edge) {
    z = h1[(size_t)kk * 32 + lane] * h1[(size_t)(kk + num_edge) * 32 + lane];
  } else {
    int i = kk - num_edge;
    z = h1[(size_t)(i % num_edge) * 32 + lane] * h1[(size_t)(2 * num_edge + i) * 32 + lane];
  }
  double a1 = 0;
#pragma unroll
  for (int d = 0; d < 32; ++d)
    a1 += (double)__shfl(z, d, 32) * (double)P1[d * 32 + lane];
  float t1 = (float)(a1 + (double)pb1[lane]);
  t1 = t1 > 0.f ? t1 : 0.f;
  double a2 = 0;
#pragma unroll
  for (int d = 0; d < 32; ++d)
    a2 += (double)__shfl(t1, d, 32) * (double)P2[d * 32 + lane];
  float t2 = (float)(a2 + (double)pb2[lane]);
  t2 = t2 > 0.f ? t2 : 0.f;
  double a3 = (double)t2 * (double)P3[lane];
#pragma unroll
  for (int off = 16; off >= 1; off >>= 1) a3 += __shfl_xor(a3, off, 64);
  if (lane == 0 && k < total) out[k] = (float)(a3 + (double)pb3[0]);
}

extern "C" void kernel_launch(void* const* d_in, const int* in_sizes, int n_in,
                              void* d_out, int out_size, void* d_ws, size_t ws_size,
                              hipStream_t stream) {
  const float* x   = (const float*)d_in[0];
  const int*   src = (const int*)d_in[1];
  const int*   dst = (const int*)d_in[2];
  const float* W0  = (const float*)d_in[4];
  const float* al0 = (const float*)d_in[5];
  const float* ar0 = (const float*)d_in[6];
  const float* b0  = (const float*)d_in[7];
  const float* W1  = (const float*)d_in[8];
  const float* al1 = (const float*)d_in[9];
  const float* ar1 = (const float*)d_in[10];
  const float* b1  = (const float*)d_in[11];
  const float* P1  = (const float*)d_in[12];
  const float* pb1 = (const float*)d_in[13];
  const float* P2  = (const float*)d_in[14];
  const float* pb2 = (const float*)d_in[15];
  const float* P3  = (const float*)d_in[16];
  const float* pb3 = (const float*)d_in[17];

  int N = in_sizes[0] / 128;
  int E = in_sizes[1];
  int num_edge = N - out_size;   // N=(2+r)*ne, out=(1+r)*ne

  size_t off = 0;
  auto alloc = [&](size_t bytes) -> void* {
    void* p = (char*)d_ws + off;
    off += (bytes + 255) & ~(size_t)255;
    return p;
  };
  unsigned short* f0h = (unsigned short*)alloc((size_t)N * 256 * 2);   // fp16 gather table
  float* f1   = (float*)alloc((size_t)N * 32 * 4);
  float* h1   = (float*)alloc((size_t)N * 32 * 4);
  float* el   = (float*)alloc((size_t)N * 8 * 4);
  float* er   = (float*)alloc((size_t)N * 8 * 4);
  float* el1  = (float*)alloc((size_t)N * 4);
  float* er1  = (float*)alloc((size_t)N * 4);
  int*   cnt  = (int*)alloc((size_t)(N + 1) * 4);   // [N] = overflow counter
  int*   bpad = (int*)alloc((size_t)N * CAPB * 4);
  int*   ovf  = (int*)alloc((size_t)E * 4);
  if (off > ws_size) return;
  int* ovf_cnt = cnt + N;

  int ngemm = (N + G0_ROWS - 1) / G0_ROWS;    // 782
  hipMemsetAsync(cnt, 0, (size_t)(N + 1) * 4, stream);
  k_gemm0_scatter<<<1792, 256, 0, stream>>>(x, W0, al0, ar0, dst, src,
                                            f0h, el, er, cnt, ovf_cnt, bpad, ovf,
                                            N, E, ngemm);
  k_fused0<<<N, 256, 0, stream>>>(el, er, f0h, cnt, ovf_cnt, bpad, ovf, dst, src, b0,
                                  W1, al1, ar1, f1, el1, er1, N);
  k_fused1<<<(N + 3) / 4, 256, 0, stream>>>(el1, er1, f1, cnt, ovf_cnt, bpad, ovf, dst,
                                            src, b1, h1, N);
  k_pred<<<(out_size + 7) / 8, 256, 0, stream>>>(h1, P1, pb1, P2, pb2, P3, pb3,
                                                 (float*)d_out, num_edge, out_size);
}